// Round 9
// baseline (334.038 us; speedup 1.0000x reference)
//
#include <hip/hip_runtime.h>

typedef unsigned short u16;
typedef __attribute__((ext_vector_type(8))) short bf16x8;
typedef __attribute__((ext_vector_type(4))) float f32x4;
typedef __attribute__((ext_vector_type(8))) unsigned short u16x8;

#define T_LEN 65536
#define HID 256
#define K0 96     // IN_DIM=72 zero-padded to 96 (multiple of 32)
#define K1 256
#define BM 128
#define BN 128
#define CHUNK 64
#define NCHUNK 1024   // T_LEN / CHUNK
#define NSEG 32
#define CPS 32        // chunks per segment

__device__ __forceinline__ float bf2f(u16 u) {
  unsigned x = ((unsigned)u) << 16; float f; __builtin_memcpy(&f, &x, 4); return f;
}
__device__ __forceinline__ u16 f2bf(float f) {
  unsigned x; __builtin_memcpy(&x, &f, 4);
  x += 0x7FFFu + ((x >> 16) & 1u);
  return (u16)(x >> 16);
}

// ---------------------------------------------------------------------------
// build x0 bf16 [T][96]: cols 0..63 = obs, 64..71 = emb[action], 72..95 = 0
// ---------------------------------------------------------------------------
__global__ __launch_bounds__(256) void build_x0(
    const float* __restrict__ obs, const int* __restrict__ act,
    const float* __restrict__ emb, u16* __restrict__ x0)
{
  const int idx = blockIdx.x * 256 + threadIdx.x;   // exactly T*24
  const int t = idx / 24, seg = idx - t * 24;
  u16 v0 = 0, v1 = 0, v2 = 0, v3 = 0;
  if (seg < 16) {
    const float4 f = *(const float4*)&obs[(size_t)t * 64 + seg * 4];
    v0 = f2bf(f.x); v1 = f2bf(f.y); v2 = f2bf(f.z); v3 = f2bf(f.w);
  } else if (seg < 18) {
    const int a = act[t];
    const int e0 = (seg - 16) * 4;
    v0 = f2bf(emb[a * 8 + e0 + 0]); v1 = f2bf(emb[a * 8 + e0 + 1]);
    v2 = f2bf(emb[a * 8 + e0 + 2]); v3 = f2bf(emb[a * 8 + e0 + 3]);
  }
  u16* p = &x0[(size_t)t * 96 + seg * 4];
  p[0] = v0; p[1] = v1; p[2] = v2; p[3] = v3;
}

// ---------------------------------------------------------------------------
// weight prep: bf16 interleaved W[4h+p][k]  (p = in/B/C/d), plus Aneg=-exp(Alog)
// ---------------------------------------------------------------------------
__global__ __launch_bounds__(256) void prep_w(
    const float* __restrict__ Win0, const float* __restrict__ WB0,
    const float* __restrict__ WC0,  const float* __restrict__ Wd0,
    const float* __restrict__ Alog0,
    const float* __restrict__ Win1, const float* __restrict__ WB1,
    const float* __restrict__ WC1,  const float* __restrict__ Wd1,
    const float* __restrict__ Alog1,
    u16* __restrict__ W0v, u16* __restrict__ W1v, float* __restrict__ Aneg)
{
  const int idx = blockIdx.x * 256 + threadIdx.x;
  if (idx < 1024 * K0) {
    const int row = idx / K0, k = idx - row * K0;
    const int h = row >> 2, p = row & 3;
    const float* W = (p == 0) ? Win0 : (p == 1) ? WB0 : (p == 2) ? WC0 : Wd0;
    W0v[idx] = f2bf((k < 72) ? W[h * 72 + k] : 0.f);
  } else if (idx < 1024 * K0 + 1024 * K1) {
    const int j = idx - 1024 * K0;
    const int row = j >> 8, k = j & 255;
    const int h = row >> 2, p = row & 3;
    const float* W = (p == 0) ? Win1 : (p == 1) ? WB1 : (p == 2) ? WC1 : Wd1;
    W1v[j] = f2bf(W[h * 256 + k]);
  } else if (idx < 1024 * K0 + 1024 * K1 + 512) {
    const int j = idx - (1024 * K0 + 1024 * K1);
    Aneg[j] = -__expf((j < 256) ? Alog0[j] : Alog1[j - 256]);
  }
}

// ---------------------------------------------------------------------------
// fused projection GEMM (bf16 MFMA) + elementwise + chunk-local scan.
// K-loop: NO LDS staging, NO barriers. Each wave loads its MFMA fragments
// directly global->register (per-lane dwordx4 at the fragment address).
// Lane pattern (l&15 rows x l>>4 16B-cols) tiles full 64B segments ->
// coalesced; wave-pair A/B row duplication is L2-absorbed. Register
// double-buffer, fully unrolled (static indexing); compiler inserts vmcnt.
// Epilogue (sT transpose + scan + packed uv store) unchanged from round 7.
// XCD-aware block decode unchanged.
// ---------------------------------------------------------------------------
template <int KDIM>
__global__ __launch_bounds__(256, 3) void gemm_scan(
    const u16* __restrict__ X, const u16* __restrict__ Wv,
    const float* __restrict__ Aneg,
    unsigned* __restrict__ uvb,
    float* __restrict__ aprod, float* __restrict__ hlast)
{
  static_assert(KDIM % 32 == 0, "K must be multiple of 32");
  constexpr int NK = KDIM / 32;
  __shared__ float sT[64 * 132];     // transpose buffer, half tile, padded
  __shared__ float sAgg[8 * 32 * 2];

  const int tid = threadIdx.x;
  const int l   = tid & 63;
  const int w   = tid >> 6;          // wave 0..3
  const int bid = blockIdx.x;        // 4096 = 512 m-tiles x 8 n-tiles
  const int xcd = bid & 7;
  const int k_  = bid >> 3;
  const int mt  = xcd * 64 + (k_ >> 3);  // m-tile 0..511
  const int nt  = k_ & 7;                // n-tile 0..7
  const int m0  = mt * BM;
  const int n0  = nt * BN;
  const int wm  = (w >> 1) * 64;     // wave quadrant
  const int wn  = (w & 1) * 64;

  f32x4 acc[4][4];
  const f32x4 zero = {0.f, 0.f, 0.f, 0.f};
#pragma unroll
  for (int mi = 0; mi < 4; ++mi)
#pragma unroll
    for (int ni = 0; ni < 4; ++ni) acc[mi][ni] = zero;

  // per-lane fragment base: row = (base + f*16 + (l&15)), k-slice (l>>4)*8 u16
  const u16* Abase = X  + (size_t)(m0 + wm + (l & 15)) * KDIM + (l >> 4) * 8;
  const u16* Bbase = Wv + (size_t)(n0 + wn + (l & 15)) * KDIM + (l >> 4) * 8;

  bf16x8 aR[2][4], bR[2][4];
#define LOADF(BUF, KS)                                                       \
  {                                                                          \
    _Pragma("unroll")                                                        \
    for (int f = 0; f < 4; ++f) {                                            \
      aR[BUF][f] = *(const bf16x8*)(Abase + (size_t)f * 16 * KDIM + (KS) * 32); \
      bR[BUF][f] = *(const bf16x8*)(Bbase + (size_t)f * 16 * KDIM + (KS) * 32); \
    }                                                                        \
  }
#define MFMA_ALL(BUF)                                                        \
  {                                                                          \
    _Pragma("unroll")                                                        \
    for (int mi = 0; mi < 4; ++mi)                                           \
      _Pragma("unroll")                                                      \
      for (int ni = 0; ni < 4; ++ni)                                         \
        acc[mi][ni] = __builtin_amdgcn_mfma_f32_16x16x32_bf16(               \
            aR[BUF][mi], bR[BUF][ni], acc[mi][ni], 0, 0, 0);                 \
  }

  LOADF(0, 0);
#pragma unroll
  for (int ks = 0; ks < NK; ++ks) {
    const int cur = ks & 1;
    if (ks + 1 < NK) LOADF(cur ^ 1, ks + 1);
    MFMA_ALL(cur);
  }
#undef LOADF
#undef MFMA_ALL

  // ---- epilogue: two halves of 64 t each (chunk = 64 t) ----
  const int q  = tid >> 5;           // 0..7 : 8-t sub-chunk
  const int c  = tid & 31;           // channel within block
  const int ch = (n0 >> 2) + c;      // global channel
  const float An = Aneg[ch];

  for (int hh = 0; hh < 2; ++hh) {
    __syncthreads();                 // prev-half sT reads done; safe to write
    if ((w >> 1) == hh) {
      // C/D layout (verified m89/m91): col = l&15 (n), row = (l>>4)*4 + v (t)
#pragma unroll
      for (int mi = 0; mi < 4; ++mi)
#pragma unroll
        for (int ni = 0; ni < 4; ++ni)
#pragma unroll
          for (int v = 0; v < 4; ++v)
            sT[(mi * 16 + (l >> 4) * 4 + v) * 132 + wn + ni * 16 + (l & 15)] = acc[mi][ni][v];
    }
    __syncthreads();

    // 8-step local scan in fp32 registers; b128 row reads
    float Pl[8], Hl[8], Cl[8];
    float ap = 1.f, hl = 0.f;
#pragma unroll
    for (int j = 0; j < 8; ++j) {
      const int tl = q * 8 + j;
      const f32x4 pv = *(const f32x4*)&sT[tl * 132 + 4 * c];
      const float delta = 1.f / (1.f + __expf(-pv[3]));
      const float a  = __expf(delta * An);
      hl = a * hl + pv[1] * pv[0];
      ap *= a;
      Pl[j] = ap; Hl[j] = hl; Cl[j] = pv[2];
    }
    sAgg[(q * 32 + c) * 2 + 0] = ap;
    sAgg[(q * 32 + c) * 2 + 1] = hl;
    __syncthreads();

    // combine sub-chunk aggregates: seed for this q from subchunks < q
    float sap = 1.f, shl = 0.f;
    for (int qq = 0; qq < q; ++qq) {
      const float a_ = sAgg[(qq * 32 + c) * 2 + 0];
      const float h_ = sAgg[(qq * 32 + c) * 2 + 1];
      shl = a_ * shl + h_;
      sap *= a_;
    }
#pragma unroll
    for (int j = 0; j < 8; ++j) {
      const int tl = q * 8 + j;
      const float hloc = Hl[j] + Pl[j] * shl;     // zero-seeded local state
      const float vpfx = Pl[j] * sap;             // chunk prefix prod
      const unsigned pack = (unsigned)f2bf(Cl[j] * hloc)
                          | ((unsigned)f2bf(Cl[j] * vpfx) << 16);
      uvb[(size_t)(m0 + hh * 64 + tl) * HID + ch] = pack;
    }
    if (q == 7) {
      const int chunk = mt * 2 + hh;
      aprod[(size_t)chunk * HID + ch] = sap * ap;            // full-chunk prod(a)
      hlast[(size_t)chunk * HID + ch] = Hl[7] + Pl[7] * shl; // zero-seeded h(63)
    }
  }
}

// ---------------------------------------------------------------------------
// pass2a: per-segment scan of chunk aggregates (32 segments x 32 chunks)
// ---------------------------------------------------------------------------
__global__ __launch_bounds__(256) void pass2a(
    const float* __restrict__ aprod, const float* __restrict__ hlast,
    float* __restrict__ clocal, float* __restrict__ apfxc,
    float* __restrict__ segAP, float* __restrict__ segHL)
{
  const int s = blockIdx.x;
  const int h = threadIdx.x;
  float H = 0.f, P = 1.f;
#pragma unroll 4
  for (int j = 0; j < CPS; ++j) {
    const size_t o = (size_t)(s * CPS + j) * HID + h;
    clocal[o] = H; apfxc[o] = P;
    const float a = aprod[o], hh = hlast[o];
    H = a * H + hh;
    P *= a;
  }
  segAP[s * HID + h] = P;
  segHL[s * HID + h] = H;
}

// pass2b: scan the 32 segment aggregates -> segc[s] = global H before segment s
__global__ __launch_bounds__(256) void pass2b(
    const float* __restrict__ segAP, const float* __restrict__ segHL,
    float* __restrict__ segc)
{
  const int h = threadIdx.x;
  float S = 0.f;
#pragma unroll 4
  for (int s = 0; s < NSEG; ++s) {
    segc[s * HID + h] = S;
    S = segAP[s * HID + h] * S + segHL[s * HID + h];
  }
}

// ---------------------------------------------------------------------------
// combine: y[t][ch] = u + v * carry,  carry = clocal + apfxc * segc (fused)
// ---------------------------------------------------------------------------
__global__ __launch_bounds__(256) void combine(
    const unsigned* __restrict__ uvb,
    const float* __restrict__ clocal, const float* __restrict__ apfxc,
    const float* __restrict__ segc, u16* __restrict__ y)
{
  const size_t vi = (size_t)blockIdx.x * 256 + threadIdx.x;  // T*HID/8 vectors
  const int t   = (int)(vi >> 5);
  const int ch0 = ((int)vi & 31) * 8;
  const int ck  = t >> 6;
  const int sg  = ck / CPS;
  const float* cl = &clocal[(size_t)ck * HID + ch0];
  const float* ax = &apfxc[(size_t)ck * HID + ch0];
  const float* sc = &segc[(size_t)sg * HID + ch0];
  const float4 cl0 = *(const float4*)&cl[0], cl1 = *(const float4*)&cl[4];
  const float4 ax0 = *(const float4*)&ax[0], ax1 = *(const float4*)&ax[4];
  const float4 sc0 = *(const float4*)&sc[0], sc1 = *(const float4*)&sc[4];
  const float crv[8] = {
    cl0.x + ax0.x * sc0.x, cl0.y + ax0.y * sc0.y,
    cl0.z + ax0.z * sc0.z, cl0.w + ax0.w * sc0.w,
    cl1.x + ax1.x * sc1.x, cl1.y + ax1.y * sc1.y,
    cl1.z + ax1.z * sc1.z, cl1.w + ax1.w * sc1.w };
  const uint4 p0 = *(const uint4*)&uvb[vi * 8];
  const uint4 p1 = *(const uint4*)&uvb[vi * 8 + 4];
  const unsigned pk[8] = {p0.x, p0.y, p0.z, p0.w, p1.x, p1.y, p1.z, p1.w};
  u16x8 o;
#pragma unroll
  for (int j = 0; j < 8; ++j)
    o[j] = f2bf(bf2f((u16)(pk[j] & 0xffffu)) + bf2f((u16)(pk[j] >> 16)) * crv[j]);
  *(u16x8*)&y[vi * 8] = o;
}

// ---------------------------------------------------------------------------
// head: out[t][o] = softplus(y1[t] . Wout[o] + bout[o]) + 1
// ---------------------------------------------------------------------------
__global__ __launch_bounds__(256) void head(
    const u16* __restrict__ y1, const float* __restrict__ Wout,
    const float* __restrict__ bout, float* __restrict__ out)
{
  __shared__ u16 ly[64 * 264];
  __shared__ float lw[4 * HID];
  __shared__ float lb[4];
  const int tid = threadIdx.x;
  for (int i = tid; i < 4 * HID; i += 256) lw[i] = Wout[i];
  if (tid < 4) lb[tid] = bout[tid];
  const size_t rbase = (size_t)blockIdx.x * 64 * HID;
#pragma unroll
  for (int i = 0; i < 8; ++i) {
    const int lin = i * 256 + tid;        // 2048 chunks of 8 bf16
    const int r = lin >> 5, c8 = lin & 31;
    *(u16x8*)&ly[r * 264 + c8 * 8] = *(const u16x8*)&y1[rbase + (size_t)r * HID + c8 * 8];
  }
  __syncthreads();
  const int t = tid >> 2, o = tid & 3;
  float acc = lb[o];
#pragma unroll 8
  for (int h = 0; h < HID; ++h)
    acc += bf2f(ly[t * 264 + h]) * lw[o * HID + h];
  out[((size_t)blockIdx.x * 64 + t) * 4 + o] = logf(1.f + __expf(acc)) + 1.f;
}

// ---------------------------------------------------------------------------
extern "C" void kernel_launch(void* const* d_in, const int* in_sizes, int n_in,
                              void* d_out, int out_size, void* d_ws, size_t ws_size,
                              hipStream_t stream)
{
  (void)in_sizes; (void)n_in; (void)out_size; (void)ws_size;
  const float* obs   = (const float*)d_in[0];
  const int*   act   = (const int*)d_in[1];
  const float* emb   = (const float*)d_in[2];
  const float* Win0  = (const float*)d_in[3];
  const float* WB0   = (const float*)d_in[4];
  const float* WC0   = (const float*)d_in[5];
  const float* Wd0   = (const float*)d_in[6];
  const float* Alog0 = (const float*)d_in[7];
  const float* Win1  = (const float*)d_in[8];
  const float* WB1   = (const float*)d_in[9];
  const float* WC1   = (const float*)d_in[10];
  const float* Wd1   = (const float*)d_in[11];
  const float* Alog1 = (const float*)d_in[12];
  const float* Wout  = (const float*)d_in[13];
  const float* bout  = (const float*)d_in[14];
  float* out = (float*)d_out;

  char* ws = (char*)d_ws;
  size_t off = 0;
  auto alloc = [&](size_t bytes) {
    char* p = ws + off;
    off += (bytes + 255) & ~(size_t)255;
    return p;
  };
  u16*      x0    = (u16*)     alloc((size_t)T_LEN * K0 * 2);   // 12.6 MB
  u16*      W0v   = (u16*)     alloc((size_t)1024 * K0 * 2);    // 0.2 MB
  u16*      W1v   = (u16*)     alloc((size_t)1024 * K1 * 2);    // 0.5 MB
  float*    Aneg  = (float*)   alloc(512 * 4);
  unsigned* uvb   = (unsigned*)alloc((size_t)T_LEN * HID * 4);  // 67 MB packed (u,v)
  u16*      y     = (u16*)     alloc((size_t)T_LEN * HID * 2);  // 33.5 MB (reused L0->L1)
  float*    aprod = (float*)   alloc((size_t)NCHUNK * HID * 4); // 1 MB
  float*    hlast = (float*)   alloc((size_t)NCHUNK * HID * 4); // 1 MB
  float*    clocal= (float*)   alloc((size_t)NCHUNK * HID * 4); // 1 MB
  float*    apfxc = (float*)   alloc((size_t)NCHUNK * HID * 4); // 1 MB
  float*    segAP = (float*)   alloc((size_t)NSEG * HID * 4);
  float*    segHL = (float*)   alloc((size_t)NSEG * HID * 4);
  float*    segc  = (float*)   alloc((size_t)NSEG * HID * 4);
  // total ~118 MB

  build_x0<<<T_LEN * 24 / 256, 256, 0, stream>>>(obs, act, emb, x0);
  prep_w<<<(1024 * K0 + 1024 * K1 + 512 + 255) / 256, 256, 0, stream>>>(
      Win0, WB0, WC0, Wd0, Alog0, Win1, WB1, WC1, Wd1, Alog1, W0v, W1v, Aneg);

  // layer 0
  gemm_scan<K0><<<4096, 256, 0, stream>>>(x0, W0v, Aneg, uvb, aprod, hlast);
  pass2a<<<NSEG, 256, 0, stream>>>(aprod, hlast, clocal, apfxc, segAP, segHL);
  pass2b<<<1, 256, 0, stream>>>(segAP, segHL, segc);
  combine<<<T_LEN * HID / 8 / 256, 256, 0, stream>>>(uvb, clocal, apfxc, segc, y);

  // layer 1
  gemm_scan<K1><<<4096, 256, 0, stream>>>(y, W1v, Aneg + 256, uvb, aprod, hlast);
  pass2a<<<NSEG, 256, 0, stream>>>(aprod, hlast, clocal, apfxc, segAP, segHL);
  pass2b<<<1, 256, 0, stream>>>(segAP, segHL, segc);
  combine<<<T_LEN * HID / 8 / 256, 256, 0, stream>>>(uvb, clocal, apfxc, segc, y);

  // output head
  head<<<T_LEN / 64, 256, 0, stream>>>(y, Wout, bout, out);
}

// Round 10
// 263.118 us; speedup vs baseline: 1.2695x; 1.2695x over previous
//
#include <hip/hip_runtime.h>

typedef unsigned short u16;
typedef __attribute__((ext_vector_type(8))) short bf16x8;
typedef __attribute__((ext_vector_type(4))) float f32x4;
typedef __attribute__((ext_vector_type(8))) unsigned short u16x8;

#define T_LEN 65536
#define HID 256
#define K0 96     // IN_DIM=72 zero-padded to 96 (multiple of 32)
#define K1 256
#define BM 128
#define BN 128
#define CHUNK 64
#define NCHUNK 1024   // T_LEN / CHUNK
#define NSEG 32
#define CPS 32        // chunks per segment

__device__ __forceinline__ float bf2f(u16 u) {
  unsigned x = ((unsigned)u) << 16; float f; __builtin_memcpy(&f, &x, 4); return f;
}
__device__ __forceinline__ u16 f2bf(float f) {
  unsigned x; __builtin_memcpy(&x, &f, 4);
  x += 0x7FFFu + ((x >> 16) & 1u);
  return (u16)(x >> 16);
}

__device__ __forceinline__ void gl_lds16(const void* g, void* l) {
  __builtin_amdgcn_global_load_lds((const __attribute__((address_space(1))) unsigned int*)g,
                                   (__attribute__((address_space(3))) unsigned int*)l,
                                   16, 0, 0);
}

// ---------------------------------------------------------------------------
// build x0 bf16 [T][96]: cols 0..63 = obs, 64..71 = emb[action], 72..95 = 0
// ---------------------------------------------------------------------------
__global__ __launch_bounds__(256) void build_x0(
    const float* __restrict__ obs, const int* __restrict__ act,
    const float* __restrict__ emb, u16* __restrict__ x0)
{
  const int idx = blockIdx.x * 256 + threadIdx.x;   // exactly T*24
  const int t = idx / 24, seg = idx - t * 24;
  u16 v0 = 0, v1 = 0, v2 = 0, v3 = 0;
  if (seg < 16) {
    const float4 f = *(const float4*)&obs[(size_t)t * 64 + seg * 4];
    v0 = f2bf(f.x); v1 = f2bf(f.y); v2 = f2bf(f.z); v3 = f2bf(f.w);
  } else if (seg < 18) {
    const int a = act[t];
    const int e0 = (seg - 16) * 4;
    v0 = f2bf(emb[a * 8 + e0 + 0]); v1 = f2bf(emb[a * 8 + e0 + 1]);
    v2 = f2bf(emb[a * 8 + e0 + 2]); v3 = f2bf(emb[a * 8 + e0 + 3]);
  }
  u16* p = &x0[(size_t)t * 96 + seg * 4];
  p[0] = v0; p[1] = v1; p[2] = v2; p[3] = v3;
}

// ---------------------------------------------------------------------------
// weight prep, SCAN-LOCAL layout: W-row r = 64*(h>>4) + 16*p + (h&15)
// (p = in/B/C/d). With the MFMA C/D mapping this puts all 4 projections of
// one channel into ONE lane (as ni=0..3), making the epilogue scan lane-local.
// Also Aneg = -exp(Alog).
// ---------------------------------------------------------------------------
__global__ __launch_bounds__(256) void prep_w(
    const float* __restrict__ Win0, const float* __restrict__ WB0,
    const float* __restrict__ WC0,  const float* __restrict__ Wd0,
    const float* __restrict__ Alog0,
    const float* __restrict__ Win1, const float* __restrict__ WB1,
    const float* __restrict__ WC1,  const float* __restrict__ Wd1,
    const float* __restrict__ Alog1,
    u16* __restrict__ W0v, u16* __restrict__ W1v, float* __restrict__ Aneg)
{
  const int idx = blockIdx.x * 256 + threadIdx.x;
  if (idx < 1024 * K0) {
    const int row = idx / K0, k = idx - row * K0;
    const int p = (row >> 4) & 3;
    const int h = (row >> 6) * 16 + (row & 15);
    const float* W = (p == 0) ? Win0 : (p == 1) ? WB0 : (p == 2) ? WC0 : Wd0;
    W0v[idx] = f2bf((k < 72) ? W[h * 72 + k] : 0.f);
  } else if (idx < 1024 * K0 + 1024 * K1) {
    const int j = idx - 1024 * K0;
    const int row = j >> 8, k = j & 255;
    const int p = (row >> 4) & 3;
    const int h = (row >> 6) * 16 + (row & 15);
    const float* W = (p == 0) ? Win1 : (p == 1) ? WB1 : (p == 2) ? WC1 : Wd1;
    W1v[j] = f2bf(W[h * 256 + k]);
  } else if (idx < 1024 * K0 + 1024 * K1 + 512) {
    const int j = idx - (1024 * K0 + 1024 * K1);
    Aneg[j] = -__expf((j < 256) ? Alog0[j] : Alog1[j - 256]);
  }
}

// ---------------------------------------------------------------------------
// fused projection GEMM (bf16 MFMA) + elementwise + chunk-local scan.
// K-loop: round-7 proven 2-phase prefetch pipeline (LDS dbuf, counted
// vmcnt(4), raw s_barrier — loads stay in flight across the barrier).
// Epilogue: FULLY IN-REGISTER (no LDS, no barriers). With the scan-local W
// layout, lane l of each wave holds all 4 projections (ni) of one channel
// (wn, l&15) at 16 t's (mi,l>>4,v). Chunk scan = 4-step local prefix per mi
// + ordered cross-lane-group compose via __shfl + lane-local mi prefix.
// Each wave owns one (chunk, 16ch) slice; lg==0 lanes write aggregates.
// ---------------------------------------------------------------------------
template <int KDIM>
__global__ __launch_bounds__(256, 4) void gemm_scan(
    const u16* __restrict__ X, const u16* __restrict__ Wv,
    const float* __restrict__ Aneg,
    unsigned* __restrict__ uvb,
    float* __restrict__ aprod, float* __restrict__ hlast)
{
  static_assert(KDIM % 32 == 0, "K must be multiple of 32");
  constexpr int NK = KDIM / 32;
  // staging dbuf only: buf0 A@0 B@8192, buf1 A@16384 B@24576
  __shared__ alignas(16) char smem[32768];

  const int tid = threadIdx.x;
  const int l   = tid & 63;
  const int w   = tid >> 6;          // wave 0..3
  const int bid = blockIdx.x;        // 4096 = 512 m-tiles x 8 n-tiles
  const int xcd = bid & 7;
  const int k_  = bid >> 3;
  const int mt  = xcd * 64 + (k_ >> 3);  // m-tile 0..511
  const int nt  = k_ & 7;                // n-tile 0..7
  const int m0  = mt * BM;
  const int n0  = nt * BN;
  const int wm  = (w >> 1) * 64;     // wave t-half (one 64-t chunk per wave)
  const int wn  = (w & 1) * 64;      // wave channel-half

  f32x4 acc[4][4];
  const f32x4 zero = {0.f, 0.f, 0.f, 0.f};
#pragma unroll
  for (int mi = 0; mi < 4; ++mi)
#pragma unroll
    for (int ni = 0; ni < 4; ++ni) acc[mi][ni] = zero;

  // staging: per wave 2 issues of 1KB per matrix; lane lands at base + l*16
  const int rr = w * 32 + (l >> 2);  // row within tile (issue i adds +16)
  const int kb = (l & 3) * 16;       // byte offset within 64B k-slice

#define STAGE(KS, BUF)                                                          \
  {                                                                             \
    _Pragma("unroll")                                                           \
    for (int i = 0; i < 2; ++i) {                                               \
      const char* gA = (const char*)(X + (size_t)(m0 + rr + i * 16) * KDIM + (KS) * 32) + kb; \
      gl_lds16(gA, smem + (BUF) * 16384 + w * 2048 + i * 1024);                 \
      const char* gB = (const char*)(Wv + (size_t)(n0 + rr + i * 16) * KDIM + (KS) * 32) + kb; \
      gl_lds16(gB, smem + (BUF) * 16384 + 8192 + w * 2048 + i * 1024);          \
    }                                                                           \
  }

  STAGE(0, 0);
  int cur = 0;
  for (int ks = 0; ks < NK; ++ks) {
    if (ks + 1 < NK) {
      STAGE(ks + 1, cur ^ 1);
      asm volatile("s_waitcnt vmcnt(4)" ::: "memory");   // my 4 old loads done
    } else {
      asm volatile("s_waitcnt vmcnt(0)" ::: "memory");
    }
    __builtin_amdgcn_s_barrier();          // all waves' old loads done
    asm volatile("" ::: "memory");

    const u16* sA = (const u16*)(smem + cur * 16384);
    const u16* sB = (const u16*)(smem + cur * 16384 + 8192);
    bf16x8 af[4], bfr[4];
#pragma unroll
    for (int mi = 0; mi < 4; ++mi)
      af[mi] = *(const bf16x8*)&sA[(wm + mi * 16 + (l & 15)) * 32 + (l >> 4) * 8];
#pragma unroll
    for (int ni = 0; ni < 4; ++ni)
      bfr[ni] = *(const bf16x8*)&sB[(wn + ni * 16 + (l & 15)) * 32 + (l >> 4) * 8];
#pragma unroll
    for (int mi = 0; mi < 4; ++mi)
#pragma unroll
      for (int ni = 0; ni < 4; ++ni)
        acc[mi][ni] = __builtin_amdgcn_mfma_f32_16x16x32_bf16(af[mi], bfr[ni], acc[mi][ni], 0, 0, 0);

    asm volatile("s_waitcnt lgkmcnt(0)" ::: "memory");   // my reads done
    __builtin_amdgcn_s_barrier();          // next STAGE may overwrite
    asm volatile("" ::: "memory");
    cur ^= 1;
  }
#undef STAGE

  // ---- epilogue: in-register chunk scan, no LDS, no barriers ----
  // acc[mi][ni][v]: t_in_chunk = mi*16 + (l>>4)*4 + v, projection = ni,
  // channel = (n0>>2) + (wn>>6)*16 + (l&15).
  const int lg = l >> 4;
  const int cc = l & 15;
  const int ch = (n0 >> 2) + (wn >> 6) * 16 + cc;
  const int chunk = mt * 2 + (wm >> 6);
  const float An = Aneg[ch];

  float Pl[4][4], Hl[4][4], Cv[4][4];    // local prefixes + C, per (mi, v)
  float P3[4], H3[4];                    // per-mi 4-step block aggregates
#pragma unroll
  for (int mi = 0; mi < 4; ++mi) {
    float ap = 1.f, hl = 0.f;
#pragma unroll
    for (int v = 0; v < 4; ++v) {
      const float pin = acc[mi][0][v];
      const float pB  = acc[mi][1][v];
      const float pC  = acc[mi][2][v];
      const float pd  = acc[mi][3][v];
      const float delta = 1.f / (1.f + __expf(-pd));
      const float a  = __expf(delta * An);
      hl = a * hl + pB * pin;
      ap *= a;
      Pl[mi][v] = ap; Hl[mi][v] = hl; Cv[mi][v] = pC;
    }
    P3[mi] = ap; H3[mi] = hl;
  }

  // ordered cross-lane-group compose: t-block index b = mi*4 + lg.
  // aL/hL: compose of blocks (mi, lg'<lg); aT/hT: compose of all 4 lg of mi.
  float aL[4], hL[4], aT[4], hT[4];
#pragma unroll
  for (int mi = 0; mi < 4; ++mi) {
    float al = 1.f, hlx = 0.f, at = 1.f, ht = 0.f;
#pragma unroll
    for (int s = 0; s < 4; ++s) {
      const float Ab = __shfl(P3[mi], cc + s * 16, 64);
      const float Hb = __shfl(H3[mi], cc + s * 16, 64);
      if (s < lg) { hlx = Ab * hlx + Hb; al *= Ab; }
      ht = Ab * ht + Hb; at *= Ab;
    }
    aL[mi] = al; hL[mi] = hlx; aT[mi] = at; hT[mi] = ht;
  }

  // lane-local prefix over mi; emit packed (u = C*hloc, v = C*apfx)
  float aM = 1.f, hM = 0.f;
#pragma unroll
  for (int mi = 0; mi < 4; ++mi) {
    const float a_pre = aL[mi] * aM;               // preMI then preLG
    const float h_pre = aL[mi] * hM + hL[mi];
#pragma unroll
    for (int v = 0; v < 4; ++v) {
      const float Pt = Pl[mi][v] * a_pre;          // chunk prefix prod at t
      const float Ht = Pl[mi][v] * h_pre + Hl[mi][v]; // zero-seeded state at t
      const unsigned pack = (unsigned)f2bf(Cv[mi][v] * Ht)
                          | ((unsigned)f2bf(Cv[mi][v] * Pt) << 16);
      uvb[(size_t)(m0 + wm + mi * 16 + lg * 4 + v) * HID + ch] = pack;
    }
    hM = aT[mi] * hM + hT[mi];
    aM *= aT[mi];
  }
  if (lg == 0) {
    aprod[(size_t)chunk * HID + ch] = aM;          // full-chunk prod(a)
    hlast[(size_t)chunk * HID + ch] = hM;          // zero-seeded h(63)
  }
}

// ---------------------------------------------------------------------------
// pass2a: per-segment scan of chunk aggregates (32 segments x 32 chunks)
// ---------------------------------------------------------------------------
__global__ __launch_bounds__(256) void pass2a(
    const float* __restrict__ aprod, const float* __restrict__ hlast,
    float* __restrict__ clocal, float* __restrict__ apfxc,
    float* __restrict__ segAP, float* __restrict__ segHL)
{
  const int s = blockIdx.x;
  const int h = threadIdx.x;
  float H = 0.f, P = 1.f;
#pragma unroll 4
  for (int j = 0; j < CPS; ++j) {
    const size_t o = (size_t)(s * CPS + j) * HID + h;
    clocal[o] = H; apfxc[o] = P;
    const float a = aprod[o], hh = hlast[o];
    H = a * H + hh;
    P *= a;
  }
  segAP[s * HID + h] = P;
  segHL[s * HID + h] = H;
}

// pass2b: scan the 32 segment aggregates -> segc[s] = global H before segment s
__global__ __launch_bounds__(256) void pass2b(
    const float* __restrict__ segAP, const float* __restrict__ segHL,
    float* __restrict__ segc)
{
  const int h = threadIdx.x;
  float S = 0.f;
#pragma unroll 4
  for (int s = 0; s < NSEG; ++s) {
    segc[s * HID + h] = S;
    S = segAP[s * HID + h] * S + segHL[s * HID + h];
  }
}

// ---------------------------------------------------------------------------
// combine: y[t][ch] = u + v * carry,  carry = clocal + apfxc * segc (fused)
// ---------------------------------------------------------------------------
__global__ __launch_bounds__(256) void combine(
    const unsigned* __restrict__ uvb,
    const float* __restrict__ clocal, const float* __restrict__ apfxc,
    const float* __restrict__ segc, u16* __restrict__ y)
{
  const size_t vi = (size_t)blockIdx.x * 256 + threadIdx.x;  // T*HID/8 vectors
  const int t   = (int)(vi >> 5);
  const int ch0 = ((int)vi & 31) * 8;
  const int ck  = t >> 6;
  const int sg  = ck / CPS;
  const float* cl = &clocal[(size_t)ck * HID + ch0];
  const float* ax = &apfxc[(size_t)ck * HID + ch0];
  const float* sc = &segc[(size_t)sg * HID + ch0];
  const float4 cl0 = *(const float4*)&cl[0], cl1 = *(const float4*)&cl[4];
  const float4 ax0 = *(const float4*)&ax[0], ax1 = *(const float4*)&ax[4];
  const float4 sc0 = *(const float4*)&sc[0], sc1 = *(const float4*)&sc[4];
  const float crv[8] = {
    cl0.x + ax0.x * sc0.x, cl0.y + ax0.y * sc0.y,
    cl0.z + ax0.z * sc0.z, cl0.w + ax0.w * sc0.w,
    cl1.x + ax1.x * sc1.x, cl1.y + ax1.y * sc1.y,
    cl1.z + ax1.z * sc1.z, cl1.w + ax1.w * sc1.w };
  const uint4 p0 = *(const uint4*)&uvb[vi * 8];
  const uint4 p1 = *(const uint4*)&uvb[vi * 8 + 4];
  const unsigned pk[8] = {p0.x, p0.y, p0.z, p0.w, p1.x, p1.y, p1.z, p1.w};
  u16x8 o;
#pragma unroll
  for (int j = 0; j < 8; ++j)
    o[j] = f2bf(bf2f((u16)(pk[j] & 0xffffu)) + bf2f((u16)(pk[j] >> 16)) * crv[j]);
  *(u16x8*)&y[vi * 8] = o;
}

// ---------------------------------------------------------------------------
// head: out[t][o] = softplus(y1[t] . Wout[o] + bout[o]) + 1
// ---------------------------------------------------------------------------
__global__ __launch_bounds__(256) void head(
    const u16* __restrict__ y1, const float* __restrict__ Wout,
    const float* __restrict__ bout, float* __restrict__ out)
{
  __shared__ u16 ly[64 * 264];
  __shared__ float lw[4 * HID];
  __shared__ float lb[4];
  const int tid = threadIdx.x;
  for (int i = tid; i < 4 * HID; i += 256) lw[i] = Wout[i];
  if (tid < 4) lb[tid] = bout[tid];
  const size_t rbase = (size_t)blockIdx.x * 64 * HID;
#pragma unroll
  for (int i = 0; i < 8; ++i) {
    const int lin = i * 256 + tid;        // 2048 chunks of 8 bf16
    const int r = lin >> 5, c8 = lin & 31;
    *(u16x8*)&ly[r * 264 + c8 * 8] = *(const u16x8*)&y1[rbase + (size_t)r * HID + c8 * 8];
  }
  __syncthreads();
  const int t = tid >> 2, o = tid & 3;
  float acc = lb[o];
#pragma unroll 8
  for (int h = 0; h < HID; ++h)
    acc += bf2f(ly[t * 264 + h]) * lw[o * HID + h];
  out[((size_t)blockIdx.x * 64 + t) * 4 + o] = logf(1.f + __expf(acc)) + 1.f;
}

// ---------------------------------------------------------------------------
extern "C" void kernel_launch(void* const* d_in, const int* in_sizes, int n_in,
                              void* d_out, int out_size, void* d_ws, size_t ws_size,
                              hipStream_t stream)
{
  (void)in_sizes; (void)n_in; (void)out_size; (void)ws_size;
  const float* obs   = (const float*)d_in[0];
  const int*   act   = (const int*)d_in[1];
  const float* emb   = (const float*)d_in[2];
  const float* Win0  = (const float*)d_in[3];
  const float* WB0   = (const float*)d_in[4];
  const float* WC0   = (const float*)d_in[5];
  const float* Wd0   = (const float*)d_in[6];
  const float* Alog0 = (const float*)d_in[7];
  const float* Win1  = (const float*)d_in[8];
  const float* WB1   = (const float*)d_in[9];
  const float* WC1   = (const float*)d_in[10];
  const float* Wd1   = (const float*)d_in[11];
  const float* Alog1 = (const float*)d_in[12];
  const float* Wout  = (const float*)d_in[13];
  const float* bout  = (const float*)d_in[14];
  float* out = (float*)d_out;

  char* ws = (char*)d_ws;
  size_t off = 0;
  auto alloc = [&](size_t bytes) {
    char* p = ws + off;
    off += (bytes + 255) & ~(size_t)255;
    return p;
  };
  u16*      x0    = (u16*)     alloc((size_t)T_LEN * K0 * 2);   // 12.6 MB
  u16*      W0v   = (u16*)     alloc((size_t)1024 * K0 * 2);    // 0.2 MB
  u16*      W1v   = (u16*)     alloc((size_t)1024 * K1 * 2);    // 0.5 MB
  float*    Aneg  = (float*)   alloc(512 * 4);
  unsigned* uvb   = (unsigned*)alloc((size_t)T_LEN * HID * 4);  // 67 MB packed (u,v)
  u16*      y     = (u16*)     alloc((size_t)T_LEN * HID * 2);  // 33.5 MB (reused L0->L1)
  float*    aprod = (float*)   alloc((size_t)NCHUNK * HID * 4); // 1 MB
  float*    hlast = (float*)   alloc((size_t)NCHUNK * HID * 4); // 1 MB
  float*    clocal= (float*)   alloc((size_t)NCHUNK * HID * 4); // 1 MB
  float*    apfxc = (float*)   alloc((size_t)NCHUNK * HID * 4); // 1 MB
  float*    segAP = (float*)   alloc((size_t)NSEG * HID * 4);
  float*    segHL = (float*)   alloc((size_t)NSEG * HID * 4);
  float*    segc  = (float*)   alloc((size_t)NSEG * HID * 4);
  // total ~118 MB

  build_x0<<<T_LEN * 24 / 256, 256, 0, stream>>>(obs, act, emb, x0);
  prep_w<<<(1024 * K0 + 1024 * K1 + 512 + 255) / 256, 256, 0, stream>>>(
      Win0, WB0, WC0, Wd0, Alog0, Win1, WB1, WC1, Wd1, Alog1, W0v, W1v, Aneg);

  // layer 0
  gemm_scan<K0><<<4096, 256, 0, stream>>>(x0, W0v, Aneg, uvb, aprod, hlast);
  pass2a<<<NSEG, 256, 0, stream>>>(aprod, hlast, clocal, apfxc, segAP, segHL);
  pass2b<<<1, 256, 0, stream>>>(segAP, segHL, segc);
  combine<<<T_LEN * HID / 8 / 256, 256, 0, stream>>>(uvb, clocal, apfxc, segc, y);

  // layer 1
  gemm_scan<K1><<<4096, 256, 0, stream>>>(y, W1v, Aneg + 256, uvb, aprod, hlast);
  pass2a<<<NSEG, 256, 0, stream>>>(aprod, hlast, clocal, apfxc, segAP, segHL);
  pass2b<<<1, 256, 0, stream>>>(segAP, segHL, segc);
  combine<<<T_LEN * HID / 8 / 256, 256, 0, stream>>>(uvb, clocal, apfxc, segc, y);

  // output head
  head<<<T_LEN / 64, 256, 0, stream>>>(y, Wout, bout, out);
}

// Round 11
// 251.262 us; speedup vs baseline: 1.3294x; 1.0472x over previous
//
#include <hip/hip_runtime.h>

typedef unsigned short u16;
typedef __attribute__((ext_vector_type(8))) short bf16x8;
typedef __attribute__((ext_vector_type(4))) float f32x4;
typedef __attribute__((ext_vector_type(8))) unsigned short u16x8;

#define T_LEN 65536
#define HID 256
#define K0 96     // IN_DIM=72 zero-padded to 96 (multiple of 32)
#define K1 256
#define BM 128
#define BN 128
#define CHUNK 64
#define NCHUNK 1024   // T_LEN / CHUNK
#define NSEG 32
#define CPS 32        // chunks per segment

__device__ __forceinline__ float bf2f(u16 u) {
  unsigned x = ((unsigned)u) << 16; float f; __builtin_memcpy(&f, &x, 4); return f;
}
__device__ __forceinline__ u16 f2bf(float f) {
  unsigned x; __builtin_memcpy(&x, &f, 4);
  x += 0x7FFFu + ((x >> 16) & 1u);
  return (u16)(x >> 16);
}

__device__ __forceinline__ void gl_lds16(const void* g, void* l) {
  __builtin_amdgcn_global_load_lds((const __attribute__((address_space(1))) unsigned int*)g,
                                   (__attribute__((address_space(3))) unsigned int*)l,
                                   16, 0, 0);
}

// ---------------------------------------------------------------------------
// build x0 bf16 [T][96]: cols 0..63 = obs, 64..71 = emb[action], 72..95 = 0
// ---------------------------------------------------------------------------
__global__ __launch_bounds__(256) void build_x0(
    const float* __restrict__ obs, const int* __restrict__ act,
    const float* __restrict__ emb, u16* __restrict__ x0)
{
  const int idx = blockIdx.x * 256 + threadIdx.x;   // exactly T*24
  const int t = idx / 24, seg = idx - t * 24;
  u16 v0 = 0, v1 = 0, v2 = 0, v3 = 0;
  if (seg < 16) {
    const float4 f = *(const float4*)&obs[(size_t)t * 64 + seg * 4];
    v0 = f2bf(f.x); v1 = f2bf(f.y); v2 = f2bf(f.z); v3 = f2bf(f.w);
  } else if (seg < 18) {
    const int a = act[t];
    const int e0 = (seg - 16) * 4;
    v0 = f2bf(emb[a * 8 + e0 + 0]); v1 = f2bf(emb[a * 8 + e0 + 1]);
    v2 = f2bf(emb[a * 8 + e0 + 2]); v3 = f2bf(emb[a * 8 + e0 + 3]);
  }
  u16* p = &x0[(size_t)t * 96 + seg * 4];
  p[0] = v0; p[1] = v1; p[2] = v2; p[3] = v3;
}

// ---------------------------------------------------------------------------
// weight prep, SCAN-LOCAL layout: W-row r = 64*(h>>4) + 16*p + (h&15)
// (p = in/B/C/d) -> all 4 projections of one channel land in ONE lane.
// Aneg = -exp(Alog).
// ---------------------------------------------------------------------------
__global__ __launch_bounds__(256) void prep_w(
    const float* __restrict__ Win0, const float* __restrict__ WB0,
    const float* __restrict__ WC0,  const float* __restrict__ Wd0,
    const float* __restrict__ Alog0,
    const float* __restrict__ Win1, const float* __restrict__ WB1,
    const float* __restrict__ WC1,  const float* __restrict__ Wd1,
    const float* __restrict__ Alog1,
    u16* __restrict__ W0v, u16* __restrict__ W1v, float* __restrict__ Aneg)
{
  const int idx = blockIdx.x * 256 + threadIdx.x;
  if (idx < 1024 * K0) {
    const int row = idx / K0, k = idx - row * K0;
    const int p = (row >> 4) & 3;
    const int h = (row >> 6) * 16 + (row & 15);
    const float* W = (p == 0) ? Win0 : (p == 1) ? WB0 : (p == 2) ? WC0 : Wd0;
    W0v[idx] = f2bf((k < 72) ? W[h * 72 + k] : 0.f);
  } else if (idx < 1024 * K0 + 1024 * K1) {
    const int j = idx - 1024 * K0;
    const int row = j >> 8, k = j & 255;
    const int p = (row >> 4) & 3;
    const int h = (row >> 6) * 16 + (row & 15);
    const float* W = (p == 0) ? Win1 : (p == 1) ? WB1 : (p == 2) ? WC1 : Wd1;
    W1v[j] = f2bf(W[h * 256 + k]);
  } else if (idx < 1024 * K0 + 1024 * K1 + 512) {
    const int j = idx - (1024 * K0 + 1024 * K1);
    Aneg[j] = -__expf((j < 256) ? Alog0[j] : Alog1[j - 256]);
  }
}

// ---------------------------------------------------------------------------
// fused projection GEMM (bf16 MFMA) + elementwise + chunk-local scan.
// K-loop: 2-phase prefetch pipeline (LDS dbuf, counted vmcnt(4), raw
// s_barrier) + LDS XOR-SWIZZLE (T2, both-sides): global source k-slice
// pre-swizzled by ((l>>3)&3), reads XOR by row-parity ((l>>1)&3) ->
// ds_read_b128 conflict-free (was 8-way).
// Epilogue: in-register chunk scan (round-10), but uvb stores are now
// WAVE-LINEAR: uvb[(bid*4+w)*1024 + (mi*4+v)*64 + l] -> 256B/instr dense.
// combine() holds the inverse index map.
// ---------------------------------------------------------------------------
template <int KDIM>
__global__ __launch_bounds__(256, 4) void gemm_scan(
    const u16* __restrict__ X, const u16* __restrict__ Wv,
    const float* __restrict__ Aneg,
    unsigned* __restrict__ uvb,
    float* __restrict__ aprod, float* __restrict__ hlast)
{
  static_assert(KDIM % 32 == 0, "K must be multiple of 32");
  constexpr int NK = KDIM / 32;
  // staging dbuf only: buf0 A@0 B@8192, buf1 A@16384 B@24576
  __shared__ alignas(16) char smem[32768];

  const int tid = threadIdx.x;
  const int l   = tid & 63;
  const int w   = tid >> 6;          // wave 0..3
  const int bid = blockIdx.x;        // 4096 = 512 m-tiles x 8 n-tiles
  const int xcd = bid & 7;
  const int k_  = bid >> 3;
  const int mt  = xcd * 64 + (k_ >> 3);  // m-tile 0..511
  const int nt  = k_ & 7;                // n-tile 0..7
  const int m0  = mt * BM;
  const int n0  = nt * BN;
  const int wm  = (w >> 1) * 64;     // wave t-half (one 64-t chunk per wave)
  const int wn  = (w & 1) * 64;      // wave channel-half

  f32x4 acc[4][4];
  const f32x4 zero = {0.f, 0.f, 0.f, 0.f};
#pragma unroll
  for (int mi = 0; mi < 4; ++mi)
#pragma unroll
    for (int ni = 0; ni < 4; ++ni) acc[mi][ni] = zero;

  // staging: per wave 2 issues of 1KB per matrix; lane lands at base + l*16.
  // LDS slot (row, kg) receives global (row, kg ^ ((row>>1)&3)); since the
  // lane's row depends only on l>>2, the source swizzle is lane-pure:
  const int rr = w * 32 + (l >> 2);  // row within tile (issue i adds +16)
  const int kb = (((l & 3) ^ ((l >> 3) & 3))) * 16;  // swizzled source k-byte

#define STAGE(KS, BUF)                                                          \
  {                                                                             \
    _Pragma("unroll")                                                           \
    for (int i = 0; i < 2; ++i) {                                               \
      const char* gA = (const char*)(X + (size_t)(m0 + rr + i * 16) * KDIM + (KS) * 32) + kb; \
      gl_lds16(gA, smem + (BUF) * 16384 + w * 2048 + i * 1024);                 \
      const char* gB = (const char*)(Wv + (size_t)(n0 + rr + i * 16) * KDIM + (KS) * 32) + kb; \
      gl_lds16(gB, smem + (BUF) * 16384 + 8192 + w * 2048 + i * 1024);          \
    }                                                                           \
  }

  // read-side swizzled k-group: kg_slot = (l>>4) ^ ((row>>1)&3), row-parity
  // term = ((l&15)>>1)&3 = (l>>1)&3 (lane-pure, same for all mi/ni)
  const int kgs = ((l >> 4) ^ ((l >> 1) & 3)) * 8;

  STAGE(0, 0);
  int cur = 0;
  for (int ks = 0; ks < NK; ++ks) {
    if (ks + 1 < NK) {
      STAGE(ks + 1, cur ^ 1);
      asm volatile("s_waitcnt vmcnt(4)" ::: "memory");   // my 4 old loads done
    } else {
      asm volatile("s_waitcnt vmcnt(0)" ::: "memory");
    }
    __builtin_amdgcn_s_barrier();          // all waves' old loads done
    asm volatile("" ::: "memory");

    const u16* sA = (const u16*)(smem + cur * 16384);
    const u16* sB = (const u16*)(smem + cur * 16384 + 8192);
    bf16x8 af[4], bfr[4];
#pragma unroll
    for (int mi = 0; mi < 4; ++mi)
      af[mi] = *(const bf16x8*)&sA[(wm + mi * 16 + (l & 15)) * 32 + kgs];
#pragma unroll
    for (int ni = 0; ni < 4; ++ni)
      bfr[ni] = *(const bf16x8*)&sB[(wn + ni * 16 + (l & 15)) * 32 + kgs];
#pragma unroll
    for (int mi = 0; mi < 4; ++mi)
#pragma unroll
      for (int ni = 0; ni < 4; ++ni)
        acc[mi][ni] = __builtin_amdgcn_mfma_f32_16x16x32_bf16(af[mi], bfr[ni], acc[mi][ni], 0, 0, 0);

    asm volatile("s_waitcnt lgkmcnt(0)" ::: "memory");   // my reads done
    __builtin_amdgcn_s_barrier();          // next STAGE may overwrite
    asm volatile("" ::: "memory");
    cur ^= 1;
  }
#undef STAGE

  // ---- epilogue: in-register chunk scan, no LDS, no barriers ----
  // acc[mi][ni][v]: t_in_chunk = mi*16 + (l>>4)*4 + v, projection = ni,
  // channel = (n0>>2) + (wn>>6)*16 + (l&15).
  const int lg = l >> 4;
  const int cc = l & 15;
  const int ch = (n0 >> 2) + (wn >> 6) * 16 + cc;
  const int chunk = mt * 2 + (wm >> 6);
  const float An = Aneg[ch];

  float Pl[4][4], Hl[4][4], Cv[4][4];    // local prefixes + C, per (mi, v)
  float P3[4], H3[4];                    // per-mi 4-step block aggregates
#pragma unroll
  for (int mi = 0; mi < 4; ++mi) {
    float ap = 1.f, hl = 0.f;
#pragma unroll
    for (int v = 0; v < 4; ++v) {
      const float pin = acc[mi][0][v];
      const float pB  = acc[mi][1][v];
      const float pC  = acc[mi][2][v];
      const float pd  = acc[mi][3][v];
      const float delta = 1.f / (1.f + __expf(-pd));
      const float a  = __expf(delta * An);
      hl = a * hl + pB * pin;
      ap *= a;
      Pl[mi][v] = ap; Hl[mi][v] = hl; Cv[mi][v] = pC;
    }
    P3[mi] = ap; H3[mi] = hl;
  }

  // ordered cross-lane-group compose: t-block index b = mi*4 + lg.
  float aL[4], hL[4], aT[4], hT[4];
#pragma unroll
  for (int mi = 0; mi < 4; ++mi) {
    float al = 1.f, hlx = 0.f, at = 1.f, ht = 0.f;
#pragma unroll
    for (int s = 0; s < 4; ++s) {
      const float Ab = __shfl(P3[mi], cc + s * 16, 64);
      const float Hb = __shfl(H3[mi], cc + s * 16, 64);
      if (s < lg) { hlx = Ab * hlx + Hb; al *= Ab; }
      ht = Ab * ht + Hb; at *= Ab;
    }
    aL[mi] = al; hL[mi] = hlx; aT[mi] = at; hT[mi] = ht;
  }

  // lane-local prefix over mi; emit packed (u = C*hloc, v = C*apfx),
  // WAVE-LINEAR store: each (mi,v) step writes 64 consecutive u32 (256B).
  unsigned* ub = uvb + ((size_t)bid * 4 + w) * 1024;
  float aM = 1.f, hM = 0.f;
#pragma unroll
  for (int mi = 0; mi < 4; ++mi) {
    const float a_pre = aL[mi] * aM;               // preMI then preLG
    const float h_pre = aL[mi] * hM + hL[mi];
#pragma unroll
    for (int v = 0; v < 4; ++v) {
      const float Pt = Pl[mi][v] * a_pre;          // chunk prefix prod at t
      const float Ht = Pl[mi][v] * h_pre + Hl[mi][v]; // zero-seeded state at t
      const unsigned pack = (unsigned)f2bf(Cv[mi][v] * Ht)
                          | ((unsigned)f2bf(Cv[mi][v] * Pt) << 16);
      ub[(mi * 4 + v) * 64 + l] = pack;
    }
    hM = aT[mi] * hM + hT[mi];
    aM *= aT[mi];
  }
  if (lg == 0) {
    aprod[(size_t)chunk * HID + ch] = aM;          // full-chunk prod(a)
    hlast[(size_t)chunk * HID + ch] = hM;          // zero-seeded h(63)
  }
}

// ---------------------------------------------------------------------------
// pass2a: per-segment scan of chunk aggregates (32 segments x 32 chunks)
// ---------------------------------------------------------------------------
__global__ __launch_bounds__(256) void pass2a(
    const float* __restrict__ aprod, const float* __restrict__ hlast,
    float* __restrict__ clocal, float* __restrict__ apfxc,
    float* __restrict__ segAP, float* __restrict__ segHL)
{
  const int s = blockIdx.x;
  const int h = threadIdx.x;
  float H = 0.f, P = 1.f;
#pragma unroll 4
  for (int j = 0; j < CPS; ++j) {
    const size_t o = (size_t)(s * CPS + j) * HID + h;
    clocal[o] = H; apfxc[o] = P;
    const float a = aprod[o], hh = hlast[o];
    H = a * H + hh;
    P *= a;
  }
  segAP[s * HID + h] = P;
  segHL[s * HID + h] = H;
}

// pass2b: scan the 32 segment aggregates -> segc[s] = global H before segment s
__global__ __launch_bounds__(256) void pass2b(
    const float* __restrict__ segAP, const float* __restrict__ segHL,
    float* __restrict__ segc)
{
  const int h = threadIdx.x;
  float S = 0.f;
#pragma unroll 4
  for (int s = 0; s < NSEG; ++s) {
    segc[s * HID + h] = S;
    S = segAP[s * HID + h] * S + segHL[s * HID + h];
  }
}

// ---------------------------------------------------------------------------
// combine: y[t][ch] = u + v * carry,  carry = clocal + apfxc * segc (fused).
// uvb is in the gemm's wave-linear layout; inverse index map:
//   mt=t>>7, tt=t&127, wmh=tt>>6, mi=(tt>>4)&3, lg=(tt>>2)&3, v=tt&3
//   nt=ch0>>5, ch5=ch0&31, wnh=ch5>>4, cc0=ch5&15
//   w=wmh*2+wnh, bid=((mt&63)*8+nt)*8+(mt>>6)
// ---------------------------------------------------------------------------
__global__ __launch_bounds__(256) void combine(
    const unsigned* __restrict__ uvb,
    const float* __restrict__ clocal, const float* __restrict__ apfxc,
    const float* __restrict__ segc, u16* __restrict__ y)
{
  const size_t vi = (size_t)blockIdx.x * 256 + threadIdx.x;  // T*HID/8 vectors
  const int t   = (int)(vi >> 5);
  const int ch0 = ((int)vi & 31) * 8;
  const int ck  = t >> 6;
  const int sg  = ck / CPS;
  const float* cl = &clocal[(size_t)ck * HID + ch0];
  const float* ax = &apfxc[(size_t)ck * HID + ch0];
  const float* sc = &segc[(size_t)sg * HID + ch0];
  const float4 cl0 = *(const float4*)&cl[0], cl1 = *(const float4*)&cl[4];
  const float4 ax0 = *(const float4*)&ax[0], ax1 = *(const float4*)&ax[4];
  const float4 sc0 = *(const float4*)&sc[0], sc1 = *(const float4*)&sc[4];
  const float crv[8] = {
    cl0.x + ax0.x * sc0.x, cl0.y + ax0.y * sc0.y,
    cl0.z + ax0.z * sc0.z, cl0.w + ax0.w * sc0.w,
    cl1.x + ax1.x * sc1.x, cl1.y + ax1.y * sc1.y,
    cl1.z + ax1.z * sc1.z, cl1.w + ax1.w * sc1.w };
  // inverse uvb index
  const int mt = t >> 7, tt = t & 127;
  const int wmh = tt >> 6, mi = (tt >> 4) & 3, lg = (tt >> 2) & 3, v = tt & 3;
  const int nt = ch0 >> 5, ch5 = ch0 & 31, wnh = ch5 >> 4, cc0 = ch5 & 15;
  const int w = wmh * 2 + wnh;
  const int bid = (((mt & 63) * 8 + nt) << 3) | (mt >> 6);
  const unsigned* up = uvb + ((size_t)bid * 4 + w) * 1024 + (mi * 4 + v) * 64
                           + lg * 16 + cc0;
  const uint4 p0 = *(const uint4*)&up[0];
  const uint4 p1 = *(const uint4*)&up[4];
  const unsigned pk[8] = {p0.x, p0.y, p0.z, p0.w, p1.x, p1.y, p1.z, p1.w};
  u16x8 o;
#pragma unroll
  for (int j = 0; j < 8; ++j)
    o[j] = f2bf(bf2f((u16)(pk[j] & 0xffffu)) + bf2f((u16)(pk[j] >> 16)) * crv[j]);
  *(u16x8*)&y[vi * 8] = o;
}

// ---------------------------------------------------------------------------
// head: out[t][o] = softplus(y1[t] . Wout[o] + bout[o]) + 1
// ---------------------------------------------------------------------------
__global__ __launch_bounds__(256) void head(
    const u16* __restrict__ y1, const float* __restrict__ Wout,
    const float* __restrict__ bout, float* __restrict__ out)
{
  __shared__ u16 ly[64 * 264];
  __shared__ float lw[4 * HID];
  __shared__ float lb[4];
  const int tid = threadIdx.x;
  for (int i = tid; i < 4 * HID; i += 256) lw[i] = Wout[i];
  if (tid < 4) lb[tid] = bout[tid];
  const size_t rbase = (size_t)blockIdx.x * 64 * HID;
#pragma unroll
  for (int i = 0; i < 8; ++i) {
    const int lin = i * 256 + tid;        // 2048 chunks of 8 bf16
    const int r = lin >> 5, c8 = lin & 31;
    *(u16x8*)&ly[r * 264 + c8 * 8] = *(const u16x8*)&y1[rbase + (size_t)r * HID + c8 * 8];
  }
  __syncthreads();
  const int t = tid >> 2, o = tid & 3;
  float acc = lb[o];
#pragma unroll 8
  for (int h = 0; h < HID; ++h)
    acc += bf2f(ly[t * 264 + h]) * lw[o * HID + h];
  out[((size_t)blockIdx.x * 64 + t) * 4 + o] = logf(1.f + __expf(acc)) + 1.f;
}

// ---------------------------------------------------------------------------
extern "C" void kernel_launch(void* const* d_in, const int* in_sizes, int n_in,
                              void* d_out, int out_size, void* d_ws, size_t ws_size,
                              hipStream_t stream)
{
  (void)in_sizes; (void)n_in; (void)out_size; (void)ws_size;
  const float* obs   = (const float*)d_in[0];
  const int*   act   = (const int*)d_in[1];
  const float* emb   = (const float*)d_in[2];
  const float* Win0  = (const float*)d_in[3];
  const float* WB0   = (const float*)d_in[4];
  const float* WC0   = (const float*)d_in[5];
  const float* Wd0   = (const float*)d_in[6];
  const float* Alog0 = (const float*)d_in[7];
  const float* Win1  = (const float*)d_in[8];
  const float* WB1   = (const float*)d_in[9];
  const float* WC1   = (const float*)d_in[10];
  const float* Wd1   = (const float*)d_in[11];
  const float* Alog1 = (const float*)d_in[12];
  const float* Wout  = (const float*)d_in[13];
  const float* bout  = (const float*)d_in[14];
  float* out = (float*)d_out;

  char* ws = (char*)d_ws;
  size_t off = 0;
  auto alloc = [&](size_t bytes) {
    char* p = ws + off;
    off += (bytes + 255) & ~(size_t)255;
    return p;
  };
  u16*      x0    = (u16*)     alloc((size_t)T_LEN * K0 * 2);   // 12.6 MB
  u16*      W0v   = (u16*)     alloc((size_t)1024 * K0 * 2);    // 0.2 MB
  u16*      W1v   = (u16*)     alloc((size_t)1024 * K1 * 2);    // 0.5 MB
  float*    Aneg  = (float*)   alloc(512 * 4);
  unsigned* uvb   = (unsigned*)alloc((size_t)T_LEN * HID * 4);  // 67 MB packed (u,v)
  u16*      y     = (u16*)     alloc((size_t)T_LEN * HID * 2);  // 33.5 MB (reused L0->L1)
  float*    aprod = (float*)   alloc((size_t)NCHUNK * HID * 4); // 1 MB
  float*    hlast = (float*)   alloc((size_t)NCHUNK * HID * 4); // 1 MB
  float*    clocal= (float*)   alloc((size_t)NCHUNK * HID * 4); // 1 MB
  float*    apfxc = (float*)   alloc((size_t)NCHUNK * HID * 4); // 1 MB
  float*    segAP = (float*)   alloc((size_t)NSEG * HID * 4);
  float*    segHL = (float*)   alloc((size_t)NSEG * HID * 4);
  float*    segc  = (float*)   alloc((size_t)NSEG * HID * 4);
  // total ~118 MB

  build_x0<<<T_LEN * 24 / 256, 256, 0, stream>>>(obs, act, emb, x0);
  prep_w<<<(1024 * K0 + 1024 * K1 + 512 + 255) / 256, 256, 0, stream>>>(
      Win0, WB0, WC0, Wd0, Alog0, Win1, WB1, WC1, Wd1, Alog1, W0v, W1v, Aneg);

  // layer 0
  gemm_scan<K0><<<4096, 256, 0, stream>>>(x0, W0v, Aneg, uvb, aprod, hlast);
  pass2a<<<NSEG, 256, 0, stream>>>(aprod, hlast, clocal, apfxc, segAP, segHL);
  pass2b<<<1, 256, 0, stream>>>(segAP, segHL, segc);
  combine<<<T_LEN * HID / 8 / 256, 256, 0, stream>>>(uvb, clocal, apfxc, segc, y);

  // layer 1
  gemm_scan<K1><<<4096, 256, 0, stream>>>(y, W1v, Aneg + 256, uvb, aprod, hlast);
  pass2a<<<NSEG, 256, 0, stream>>>(aprod, hlast, clocal, apfxc, segAP, segHL);
  pass2b<<<1, 256, 0, stream>>>(segAP, segHL, segc);
  combine<<<T_LEN * HID / 8 / 256, 256, 0, stream>>>(uvb, clocal, apfxc, segc, y);

  // output head
  head<<<T_LEN / 64, 256, 0, stream>>>(y, Wout, bout, out);
}

// Round 12
// 244.100 us; speedup vs baseline: 1.3685x; 1.0293x over previous
//
#include <hip/hip_runtime.h>

typedef unsigned short u16;
typedef __attribute__((ext_vector_type(8))) short bf16x8;
typedef __attribute__((ext_vector_type(4))) float f32x4;
typedef __attribute__((ext_vector_type(8))) unsigned short u16x8;

#define T_LEN 65536
#define HID 256
#define K0 96     // IN_DIM=72 zero-padded to 96 (multiple of 32)
#define K1 256
#define BM 128
#define BN 128
#define CHUNK 64
#define NCHUNK 1024   // T_LEN / CHUNK
#define NSEG 32
#define CPS 32        // chunks per segment

__device__ __forceinline__ float bf2f(u16 u) {
  unsigned x = ((unsigned)u) << 16; float f; __builtin_memcpy(&f, &x, 4); return f;
}
__device__ __forceinline__ u16 f2bf(float f) {
  unsigned x; __builtin_memcpy(&x, &f, 4);
  x += 0x7FFFu + ((x >> 16) & 1u);
  return (u16)(x >> 16);
}

__device__ __forceinline__ void gl_lds16(const void* g, void* l) {
  __builtin_amdgcn_global_load_lds((const __attribute__((address_space(1))) unsigned int*)g,
                                   (__attribute__((address_space(3))) unsigned int*)l,
                                   16, 0, 0);
}

// ---------------------------------------------------------------------------
// prep_all: fused input build + weight prep (one dispatch).
// x0 bf16 [T][96]: cols 0..63 = obs, 64..71 = emb[action], 72..95 = 0.
// W layout SCAN-LOCAL: W-row r = 64*(h>>4) + 16*p + (h&15) (p = in/B/C/d)
// -> all 4 projections of one channel land in ONE lane of the MFMA C/D.
// Aneg = -exp(Alog).
// ---------------------------------------------------------------------------
#define NX (T_LEN * 24)
__global__ __launch_bounds__(256) void prep_all(
    const float* __restrict__ obs, const int* __restrict__ act,
    const float* __restrict__ emb,
    const float* __restrict__ Win0, const float* __restrict__ WB0,
    const float* __restrict__ WC0,  const float* __restrict__ Wd0,
    const float* __restrict__ Alog0,
    const float* __restrict__ Win1, const float* __restrict__ WB1,
    const float* __restrict__ WC1,  const float* __restrict__ Wd1,
    const float* __restrict__ Alog1,
    u16* __restrict__ x0, u16* __restrict__ W0v, u16* __restrict__ W1v,
    float* __restrict__ Aneg)
{
  int idx = blockIdx.x * 256 + threadIdx.x;
  if (idx < NX) {
    const int t = idx / 24, seg = idx - t * 24;
    u16 v0 = 0, v1 = 0, v2 = 0, v3 = 0;
    if (seg < 16) {
      const float4 f = *(const float4*)&obs[(size_t)t * 64 + seg * 4];
      v0 = f2bf(f.x); v1 = f2bf(f.y); v2 = f2bf(f.z); v3 = f2bf(f.w);
    } else if (seg < 18) {
      const int a = act[t];
      const int e0 = (seg - 16) * 4;
      v0 = f2bf(emb[a * 8 + e0 + 0]); v1 = f2bf(emb[a * 8 + e0 + 1]);
      v2 = f2bf(emb[a * 8 + e0 + 2]); v3 = f2bf(emb[a * 8 + e0 + 3]);
    }
    u16* p = &x0[(size_t)t * 96 + seg * 4];
    p[0] = v0; p[1] = v1; p[2] = v2; p[3] = v3;
    return;
  }
  idx -= NX;
  if (idx < 1024 * K0) {
    const int row = idx / K0, k = idx - row * K0;
    const int p = (row >> 4) & 3;
    const int h = (row >> 6) * 16 + (row & 15);
    const float* W = (p == 0) ? Win0 : (p == 1) ? WB0 : (p == 2) ? WC0 : Wd0;
    W0v[idx] = f2bf((k < 72) ? W[h * 72 + k] : 0.f);
  } else if (idx < 1024 * K0 + 1024 * K1) {
    const int j = idx - 1024 * K0;
    const int row = j >> 8, k = j & 255;
    const int p = (row >> 4) & 3;
    const int h = (row >> 6) * 16 + (row & 15);
    const float* W = (p == 0) ? Win1 : (p == 1) ? WB1 : (p == 2) ? WC1 : Wd1;
    W1v[j] = f2bf(W[h * 256 + k]);
  } else if (idx < 1024 * K0 + 1024 * K1 + 512) {
    const int j = idx - (1024 * K0 + 1024 * K1);
    Aneg[j] = -__expf((j < 256) ? Alog0[j] : Alog1[j - 256]);
  }
}

// ---------------------------------------------------------------------------
// fused projection GEMM (bf16 MFMA) + elementwise + chunk-local scan.
// K-loop: DEPTH-2 prefetch pipeline, 3 LDS buffers (48KB): stage ks+2 is
// issued while stages ks+1, ks+2 stay in flight; counted vmcnt(8/4/0) waits
// only for stage ks. Loads get ~2 iterations to land (targets the measured
// latency exposure: K0(NK=3) == K1(NK=8) time at depth-1).
// LDS XOR-swizzle (r11, conflict-free ds_read_b128) retained.
// Epilogue: in-register chunk scan, wave-linear dense uvb stores (r11).
// ---------------------------------------------------------------------------
template <int KDIM>
__global__ __launch_bounds__(256, 3) void gemm_scan(
    const u16* __restrict__ X, const u16* __restrict__ Wv,
    const float* __restrict__ Aneg,
    unsigned* __restrict__ uvb,
    float* __restrict__ aprod, float* __restrict__ hlast)
{
  static_assert(KDIM % 32 == 0, "K must be multiple of 32");
  constexpr int NK = KDIM / 32;
  // 3 staging buffers: buf i = smem + i*16384 {A@0, B@8192}
  __shared__ alignas(16) char smem[49152];

  const int tid = threadIdx.x;
  const int l   = tid & 63;
  const int w   = tid >> 6;          // wave 0..3
  const int bid = blockIdx.x;        // 4096 = 512 m-tiles x 8 n-tiles
  const int xcd = bid & 7;
  const int k_  = bid >> 3;
  const int mt  = xcd * 64 + (k_ >> 3);  // m-tile 0..511
  const int nt  = k_ & 7;                // n-tile 0..7
  const int m0  = mt * BM;
  const int n0  = nt * BN;
  const int wm  = (w >> 1) * 64;     // wave t-half (one 64-t chunk per wave)
  const int wn  = (w & 1) * 64;      // wave channel-half

  f32x4 acc[4][4];
  const f32x4 zero = {0.f, 0.f, 0.f, 0.f};
#pragma unroll
  for (int mi = 0; mi < 4; ++mi)
#pragma unroll
    for (int ni = 0; ni < 4; ++ni) acc[mi][ni] = zero;

  // staging: per wave 2 issues of 1KB per matrix; lane lands at base + l*16.
  // Source k-slice pre-swizzled (lane-pure) so swizzled reads are linear:
  const int rr = w * 32 + (l >> 2);  // row within tile (issue i adds +16)
  const int kb = (((l & 3) ^ ((l >> 3) & 3))) * 16;  // swizzled source k-byte

#define STAGE(KS, BUF)                                                          \
  {                                                                             \
    _Pragma("unroll")                                                           \
    for (int i = 0; i < 2; ++i) {                                               \
      const char* gA = (const char*)(X + (size_t)(m0 + rr + i * 16) * KDIM + (KS) * 32) + kb; \
      gl_lds16(gA, smem + (BUF) * 16384 + w * 2048 + i * 1024);                 \
      const char* gB = (const char*)(Wv + (size_t)(n0 + rr + i * 16) * KDIM + (KS) * 32) + kb; \
      gl_lds16(gB, smem + (BUF) * 16384 + 8192 + w * 2048 + i * 1024);          \
    }                                                                           \
  }

  // read-side swizzled k-group (row-parity term (l>>1)&3 is lane-pure)
  const int kgs = ((l >> 4) ^ ((l >> 1) & 3)) * 8;

  STAGE(0, 0);
  if (NK > 1) STAGE(1, 1);
#pragma unroll
  for (int ks = 0; ks < NK; ++ks) {
    if (ks + 2 < NK) STAGE(ks + 2, (ks + 2) % 3);
    const int rem = NK - 1 - ks;     // stages still in flight beyond ks
    if (rem >= 2)      asm volatile("s_waitcnt vmcnt(8)" ::: "memory");
    else if (rem == 1) asm volatile("s_waitcnt vmcnt(4)" ::: "memory");
    else               asm volatile("s_waitcnt vmcnt(0)" ::: "memory");
    __builtin_amdgcn_s_barrier();          // all waves' stage-ks loads done
    asm volatile("" ::: "memory");

    const u16* sA = (const u16*)(smem + (ks % 3) * 16384);
    const u16* sB = (const u16*)(smem + (ks % 3) * 16384 + 8192);
    bf16x8 af[4], bfr[4];
#pragma unroll
    for (int mi = 0; mi < 4; ++mi)
      af[mi] = *(const bf16x8*)&sA[(wm + mi * 16 + (l & 15)) * 32 + kgs];
#pragma unroll
    for (int ni = 0; ni < 4; ++ni)
      bfr[ni] = *(const bf16x8*)&sB[(wn + ni * 16 + (l & 15)) * 32 + kgs];
#pragma unroll
    for (int mi = 0; mi < 4; ++mi)
#pragma unroll
      for (int ni = 0; ni < 4; ++ni)
        acc[mi][ni] = __builtin_amdgcn_mfma_f32_16x16x32_bf16(af[mi], bfr[ni], acc[mi][ni], 0, 0, 0);

    asm volatile("s_waitcnt lgkmcnt(0)" ::: "memory");   // my reads done
    __builtin_amdgcn_s_barrier();          // buf[(ks)%3] may be overwritten at ks+1
    asm volatile("" ::: "memory");
  }
#undef STAGE

  // ---- epilogue: in-register chunk scan, no LDS, no barriers ----
  // acc[mi][ni][v]: t_in_chunk = mi*16 + (l>>4)*4 + v, projection = ni,
  // channel = (n0>>2) + (wn>>6)*16 + (l&15).
  const int lg = l >> 4;
  const int cc = l & 15;
  const int ch = (n0 >> 2) + (wn >> 6) * 16 + cc;
  const int chunk = mt * 2 + (wm >> 6);
  const float An = Aneg[ch];

  float Pl[4][4], Hl[4][4], Cv[4][4];    // local prefixes + C, per (mi, v)
  float P3[4], H3[4];                    // per-mi 4-step block aggregates
#pragma unroll
  for (int mi = 0; mi < 4; ++mi) {
    float ap = 1.f, hl = 0.f;
#pragma unroll
    for (int v = 0; v < 4; ++v) {
      const float pin = acc[mi][0][v];
      const float pB  = acc[mi][1][v];
      const float pC  = acc[mi][2][v];
      const float pd  = acc[mi][3][v];
      const float delta = 1.f / (1.f + __expf(-pd));
      const float a  = __expf(delta * An);
      hl = a * hl + pB * pin;
      ap *= a;
      Pl[mi][v] = ap; Hl[mi][v] = hl; Cv[mi][v] = pC;
    }
    P3[mi] = ap; H3[mi] = hl;
  }

  // ordered cross-lane-group compose: t-block index b = mi*4 + lg.
  float aL[4], hL[4], aT[4], hT[4];
#pragma unroll
  for (int mi = 0; mi < 4; ++mi) {
    float al = 1.f, hlx = 0.f, at = 1.f, ht = 0.f;
#pragma unroll
    for (int s = 0; s < 4; ++s) {
      const float Ab = __shfl(P3[mi], cc + s * 16, 64);
      const float Hb = __shfl(H3[mi], cc + s * 16, 64);
      if (s < lg) { hlx = Ab * hlx + Hb; al *= Ab; }
      ht = Ab * ht + Hb; at *= Ab;
    }
    aL[mi] = al; hL[mi] = hlx; aT[mi] = at; hT[mi] = ht;
  }

  // lane-local prefix over mi; emit packed (u = C*hloc, v = C*apfx),
  // WAVE-LINEAR store: each (mi,v) step writes 64 consecutive u32 (256B).
  unsigned* ub = uvb + ((size_t)bid * 4 + w) * 1024;
  float aM = 1.f, hM = 0.f;
#pragma unroll
  for (int mi = 0; mi < 4; ++mi) {
    const float a_pre = aL[mi] * aM;               // preMI then preLG
    const float h_pre = aL[mi] * hM + hL[mi];
#pragma unroll
    for (int v = 0; v < 4; ++v) {
      const float Pt = Pl[mi][v] * a_pre;          // chunk prefix prod at t
      const float Ht = Pl[mi][v] * h_pre + Hl[mi][v]; // zero-seeded state at t
      const unsigned pack = (unsigned)f2bf(Cv[mi][v] * Ht)
                          | ((unsigned)f2bf(Cv[mi][v] * Pt) << 16);
      ub[(mi * 4 + v) * 64 + l] = pack;
    }
    hM = aT[mi] * hM + hT[mi];
    aM *= aT[mi];
  }
  if (lg == 0) {
    aprod[(size_t)chunk * HID + ch] = aM;          // full-chunk prod(a)
    hlast[(size_t)chunk * HID + ch] = hM;          // zero-seeded h(63)
  }
}

// ---------------------------------------------------------------------------
// pass2a: per-segment scan of chunk aggregates (32 segments x 32 chunks)
// ---------------------------------------------------------------------------
__global__ __launch_bounds__(256) void pass2a(
    const float* __restrict__ aprod, const float* __restrict__ hlast,
    float* __restrict__ clocal, float* __restrict__ apfxc,
    float* __restrict__ segAP, float* __restrict__ segHL)
{
  const int s = blockIdx.x;
  const int h = threadIdx.x;
  float H = 0.f, P = 1.f;
#pragma unroll 4
  for (int j = 0; j < CPS; ++j) {
    const size_t o = (size_t)(s * CPS + j) * HID + h;
    clocal[o] = H; apfxc[o] = P;
    const float a = aprod[o], hh = hlast[o];
    H = a * H + hh;
    P *= a;
  }
  segAP[s * HID + h] = P;
  segHL[s * HID + h] = H;
}

// pass2b: scan the 32 segment aggregates -> segc[s] = global H before segment s
__global__ __launch_bounds__(256) void pass2b(
    const float* __restrict__ segAP, const float* __restrict__ segHL,
    float* __restrict__ segc)
{
  const int h = threadIdx.x;
  float S = 0.f;
#pragma unroll 4
  for (int s = 0; s < NSEG; ++s) {
    segc[s * HID + h] = S;
    S = segAP[s * HID + h] * S + segHL[s * HID + h];
  }
}

// ---------------------------------------------------------------------------
// combine: y[t][ch] = u + v * carry,  carry = clocal + apfxc * segc (fused).
// uvb is in the gemm's wave-linear layout; inverse index map:
//   mt=t>>7, tt=t&127, wmh=tt>>6, mi=(tt>>4)&3, lg=(tt>>2)&3, v=tt&3
//   nt=ch0>>5, ch5=ch0&31, wnh=ch5>>4, cc0=ch5&15
//   w=wmh*2+wnh, bid=((mt&63)*8+nt)*8+(mt>>6)
// ---------------------------------------------------------------------------
__global__ __launch_bounds__(256) void combine(
    const unsigned* __restrict__ uvb,
    const float* __restrict__ clocal, const float* __restrict__ apfxc,
    const float* __restrict__ segc, u16* __restrict__ y)
{
  const size_t vi = (size_t)blockIdx.x * 256 + threadIdx.x;  // T*HID/8 vectors
  const int t   = (int)(vi >> 5);
  const int ch0 = ((int)vi & 31) * 8;
  const int ck  = t >> 6;
  const int sg  = ck / CPS;
  const float* cl = &clocal[(size_t)ck * HID + ch0];
  const float* ax = &apfxc[(size_t)ck * HID + ch0];
  const float* sc = &segc[(size_t)sg * HID + ch0];
  const float4 cl0 = *(const float4*)&cl[0], cl1 = *(const float4*)&cl[4];
  const float4 ax0 = *(const float4*)&ax[0], ax1 = *(const float4*)&ax[4];
  const float4 sc0 = *(const float4*)&sc[0], sc1 = *(const float4*)&sc[4];
  const float crv[8] = {
    cl0.x + ax0.x * sc0.x, cl0.y + ax0.y * sc0.y,
    cl0.z + ax0.z * sc0.z, cl0.w + ax0.w * sc0.w,
    cl1.x + ax1.x * sc1.x, cl1.y + ax1.y * sc1.y,
    cl1.z + ax1.z * sc1.z, cl1.w + ax1.w * sc1.w };
  // inverse uvb index
  const int mt = t >> 7, tt = t & 127;
  const int wmh = tt >> 6, mi = (tt >> 4) & 3, lg = (tt >> 2) & 3, v = tt & 3;
  const int nt = ch0 >> 5, ch5 = ch0 & 31, wnh = ch5 >> 4, cc0 = ch5 & 15;
  const int w = wmh * 2 + wnh;
  const int bid = (((mt & 63) * 8 + nt) << 3) | (mt >> 6);
  const unsigned* up = uvb + ((size_t)bid * 4 + w) * 1024 + (mi * 4 + v) * 64
                           + lg * 16 + cc0;
  const uint4 p0 = *(const uint4*)&up[0];
  const uint4 p1 = *(const uint4*)&up[4];
  const unsigned pk[8] = {p0.x, p0.y, p0.z, p0.w, p1.x, p1.y, p1.z, p1.w};
  u16x8 o;
#pragma unroll
  for (int j = 0; j < 8; ++j)
    o[j] = f2bf(bf2f((u16)(pk[j] & 0xffffu)) + bf2f((u16)(pk[j] >> 16)) * crv[j]);
  *(u16x8*)&y[vi * 8] = o;
}

// ---------------------------------------------------------------------------
// head: out[t][o] = softplus(y1[t] . Wout[o] + bout[o]) + 1
// ---------------------------------------------------------------------------
__global__ __launch_bounds__(256) void head(
    const u16* __restrict__ y1, const float* __restrict__ Wout,
    const float* __restrict__ bout, float* __restrict__ out)
{
  __shared__ u16 ly[64 * 264];
  __shared__ float lw[4 * HID];
  __shared__ float lb[4];
  const int tid = threadIdx.x;
  for (int i = tid; i < 4 * HID; i += 256) lw[i] = Wout[i];
  if (tid < 4) lb[tid] = bout[tid];
  const size_t rbase = (size_t)blockIdx.x * 64 * HID;
#pragma unroll
  for (int i = 0; i < 8; ++i) {
    const int lin = i * 256 + tid;        // 2048 chunks of 8 bf16
    const int r = lin >> 5, c8 = lin & 31;
    *(u16x8*)&ly[r * 264 + c8 * 8] = *(const u16x8*)&y1[rbase + (size_t)r * HID + c8 * 8];
  }
  __syncthreads();
  const int t = tid >> 2, o = tid & 3;
  float acc = lb[o];
#pragma unroll 8
  for (int h = 0; h < HID; ++h)
    acc += bf2f(ly[t * 264 + h]) * lw[o * HID + h];
  out[((size_t)blockIdx.x * 64 + t) * 4 + o] = logf(1.f + __expf(acc)) + 1.f;
}

// ---------------------------------------------------------------------------
extern "C" void kernel_launch(void* const* d_in, const int* in_sizes, int n_in,
                              void* d_out, int out_size, void* d_ws, size_t ws_size,
                              hipStream_t stream)
{
  (void)in_sizes; (void)n_in; (void)out_size; (void)ws_size;
  const float* obs   = (const float*)d_in[0];
  const int*   act   = (const int*)d_in[1];
  const float* emb   = (const float*)d_in[2];
  const float* Win0  = (const float*)d_in[3];
  const float* WB0   = (const float*)d_in[4];
  const float* WC0   = (const float*)d_in[5];
  const float* Wd0   = (const float*)d_in[6];
  const float* Alog0 = (const float*)d_in[7];
  const float* Win1  = (const float*)d_in[8];
  const float* WB1   = (const float*)d_in[9];
  const float* WC1   = (const float*)d_in[10];
  const float* Wd1   = (const float*)d_in[11];
  const float* Alog1 = (const float*)d_in[12];
  const float* Wout  = (const float*)d_in[13];
  const float* bout  = (const float*)d_in[14];
  float* out = (float*)d_out;

  char* ws = (char*)d_ws;
  size_t off = 0;
  auto alloc = [&](size_t bytes) {
    char* p = ws + off;
    off += (bytes + 255) & ~(size_t)255;
    return p;
  };
  u16*      x0    = (u16*)     alloc((size_t)T_LEN * K0 * 2);   // 12.6 MB
  u16*      W0v   = (u16*)     alloc((size_t)1024 * K0 * 2);    // 0.2 MB
  u16*      W1v   = (u16*)     alloc((size_t)1024 * K1 * 2);    // 0.5 MB
  float*    Aneg  = (float*)   alloc(512 * 4);
  unsigned* uvb   = (unsigned*)alloc((size_t)T_LEN * HID * 4);  // 67 MB packed (u,v)
  u16*      y     = (u16*)     alloc((size_t)T_LEN * HID * 2);  // 33.5 MB (reused L0->L1)
  float*    aprod = (float*)   alloc((size_t)NCHUNK * HID * 4); // 1 MB
  float*    hlast = (float*)   alloc((size_t)NCHUNK * HID * 4); // 1 MB
  float*    clocal= (float*)   alloc((size_t)NCHUNK * HID * 4); // 1 MB
  float*    apfxc = (float*)   alloc((size_t)NCHUNK * HID * 4); // 1 MB
  float*    segAP = (float*)   alloc((size_t)NSEG * HID * 4);
  float*    segHL = (float*)   alloc((size_t)NSEG * HID * 4);
  float*    segc  = (float*)   alloc((size_t)NSEG * HID * 4);
  // total ~118 MB

  const int prep_threads = NX + 1024 * K0 + 1024 * K1 + 512;
  prep_all<<<(prep_threads + 255) / 256, 256, 0, stream>>>(
      obs, act, emb,
      Win0, WB0, WC0, Wd0, Alog0, Win1, WB1, WC1, Wd1, Alog1,
      x0, W0v, W1v, Aneg);

  // layer 0
  gemm_scan<K0><<<4096, 256, 0, stream>>>(x0, W0v, Aneg, uvb, aprod, hlast);
  pass2a<<<NSEG, 256, 0, stream>>>(aprod, hlast, clocal, apfxc, segAP, segHL);
  pass2b<<<1, 256, 0, stream>>>(segAP, segHL, segc);
  combine<<<T_LEN * HID / 8 / 256, 256, 0, stream>>>(uvb, clocal, apfxc, segc, y);

  // layer 1
  gemm_scan<K1><<<4096, 256, 0, stream>>>(y, W1v, Aneg + 256, uvb, aprod, hlast);
  pass2a<<<NSEG, 256, 0, stream>>>(aprod, hlast, clocal, apfxc, segAP, segHL);
  pass2b<<<1, 256, 0, stream>>>(segAP, segHL, segc);
  combine<<<T_LEN * HID / 8 / 256, 256, 0, stream>>>(uvb, clocal, apfxc, segc, y);

  // output head
  head<<<T_LEN / 64, 256, 0, stream>>>(y, Wout, bout, out);
}